// Round 7
// baseline (317.336 us; speedup 1.0000x reference)
//
#include <hip/hip_runtime.h>
#include <hip/hip_bf16.h>

#define DF 256
#define KC 64

typedef __attribute__((ext_vector_type(8))) short short8v;
typedef __attribute__((ext_vector_type(4))) float float4v;

__device__ __forceinline__ float waveReduceSum(float v) {
    #pragma unroll
    for (int off = 32; off; off >>= 1) v += __shfl_xor(v, off, 64);
    return v;
}

__device__ __forceinline__ float ldS(const float* p) { return *p; }
__device__ __forceinline__ float ldS(const __hip_bfloat16* p) { return __bfloat162float(*p); }

__device__ __forceinline__ void splitbf(float f, short& hi, short& lo) {
    unsigned u = __float_as_uint(f);
    hi = (short)(u >> 16);                       // truncated bf16 hi
    float r = f - __uint_as_float(u & 0xFFFF0000u);
    __hip_bfloat16 lb = __float2bfloat16(r);     // RNE lo
    lo = *reinterpret_cast<short*>(&lb);
}

// ---------------- sentinel fill (f32) ----------------
__global__ void k_sentinel(float* __restrict__ out, float val, int n) {
    int i = blockIdx.x * blockDim.x + threadIdx.x;
    int st = gridDim.x * blockDim.x;
    for (; i < n; i += st) out[i] = val;
}

// ---------------- K0: zero small accumulator region in ws ----------------
__global__ void k_zero(float* __restrict__ p, int n) {
    int i = blockIdx.x * blockDim.x + threadIdx.x;
    int st = gridDim.x * blockDim.x;
    for (; i < n; i += st) p[i] = 0.f;
}

// ---------------- prep: W [256][64] f32 -> frag-packed bf16 hi/lo ----------------
__global__ void k_prepW(const float* __restrict__ W, ushort* __restrict__ W2) {
    int i = blockIdx.x * blockDim.x + threadIdx.x;
    if (i >= DF * KC) return;
    int k = i >> 6, c = i & 63;
    int kk = k >> 5, g = (k >> 3) & 3, j = k & 7;
    int dst = ((kk * 4 + g) * 64 + c) * 8 + j;
    short hi, lo;
    splitbf(W[i], hi, lo);
    W2[dst] = (ushort)hi;
    W2[DF * KC + dst] = (ushort)lo;
}

// ---------------- K1 (MFMA): logits = F@W + b (split-bf16 x3), softmax, cs ----
// S16 shadow written K-SPLIT: Sh[half][n][32] for L2-resident edge gathers.
__global__ __launch_bounds__(256) void k_assign_mfma(
    const float* __restrict__ F, const ushort* __restrict__ W2,
    const float* __restrict__ Bias, float* __restrict__ S,
    __hip_bfloat16* __restrict__ S16, float* __restrict__ cs,
    int N, int writeBf16)
{
    __shared__ ushort W2s[2 * DF * KC];   // 64 KB: hi [0..16384), lo [16384..)
    {
        const int4* src = (const int4*)W2;
        int4* dst = (int4*)W2s;
        for (int i = threadIdx.x; i < 4096; i += 256) dst[i] = src[i];
    }
    __syncthreads();
    const int lane = threadIdx.x & 63;
    const int wv = threadIdx.x >> 6;
    const int lw = lane & 15, g = lane >> 4;
    const int NT = (N + 15) >> 4;
    const int t = blockIdx.x * 4 + wv;
    if (t < NT) {
        const int r0 = t * 16;
        int arowi = r0 + lw; if (arowi >= N) arowi = N - 1;
        const float* arow = F + (size_t)arowi * DF + g * 8;
        short8v ahi[8], alo[8];
        #pragma unroll
        for (int kk = 0; kk < 8; ++kk) {
            float4 x = *(const float4*)(arow + kk * 32);
            float4 y = *(const float4*)(arow + kk * 32 + 4);
            float xf[8] = {x.x, x.y, x.z, x.w, y.x, y.y, y.z, y.w};
            #pragma unroll
            for (int j = 0; j < 8; ++j) {
                short hi, lo; splitbf(xf[j], hi, lo);
                ahi[kk][j] = hi; alo[kk][j] = lo;
            }
        }
        float4v acc[4];
        #pragma unroll
        for (int ct = 0; ct < 4; ++ct) {
            float bv = Bias[ct * 16 + lw];
            acc[ct] = float4v{bv, bv, bv, bv};
        }
        #pragma unroll
        for (int kk = 0; kk < 8; ++kk) {
            #pragma unroll
            for (int ct = 0; ct < 4; ++ct) {
                int eb = ((kk * 4 + g) * 64 + ct * 16 + lw) * 8;
                short8v bhi = *(short8v*)(&W2s[eb]);
                short8v blo = *(short8v*)(&W2s[DF * KC + eb]);
                acc[ct] = __builtin_amdgcn_mfma_f32_16x16x32_bf16(ahi[kk], bhi, acc[ct], 0, 0, 0);
                acc[ct] = __builtin_amdgcn_mfma_f32_16x16x32_bf16(ahi[kk], blo, acc[ct], 0, 0, 0);
                acc[ct] = __builtin_amdgcn_mfma_f32_16x16x32_bf16(alo[kk], bhi, acc[ct], 0, 0, 0);
            }
        }
        float csp[4] = {0.f, 0.f, 0.f, 0.f};
        const size_t halfStride = (size_t)N * 32;
        #pragma unroll
        for (int r = 0; r < 4; ++r) {
            float m = fmaxf(fmaxf(acc[0][r], acc[1][r]), fmaxf(acc[2][r], acc[3][r]));
            #pragma unroll
            for (int off = 8; off; off >>= 1) m = fmaxf(m, __shfl_xor(m, off, 64));
            float e0 = expf(acc[0][r] - m), e1 = expf(acc[1][r] - m);
            float e2 = expf(acc[2][r] - m), e3 = expf(acc[3][r] - m);
            float s = e0 + e1 + e2 + e3;
            #pragma unroll
            for (int off = 8; off; off >>= 1) s += __shfl_xor(s, off, 64);
            float inv = 1.f / s;
            e0 *= inv; e1 *= inv; e2 *= inv; e3 *= inv;
            int rw = r0 + g * 4 + r;
            if (rw < N) {
                size_t base = (size_t)rw * KC + lw;
                S[base +  0] = e0; S[base + 16] = e1;
                S[base + 32] = e2; S[base + 48] = e3;
                if (writeBf16) {
                    size_t hb = (size_t)rw * 32 + lw;
                    S16[hb +  0]              = __float2bfloat16(e0);   // k = lw
                    S16[hb + 16]              = __float2bfloat16(e1);   // k = 16+lw
                    S16[halfStride + hb +  0] = __float2bfloat16(e2);   // k = 32+lw
                    S16[halfStride + hb + 16] = __float2bfloat16(e3);   // k = 48+lw
                }
                csp[0] += e0; csp[1] += e1; csp[2] += e2; csp[3] += e3;
            }
        }
        #pragma unroll
        for (int ct = 0; ct < 4; ++ct) {
            csp[ct] += __shfl_xor(csp[ct], 16, 64);
            csp[ct] += __shfl_xor(csp[ct], 32, 64);
        }
        if (g == 0) {
            #pragma unroll
            for (int ct = 0; ct < 4; ++ct) atomicAdd(cs + ct * 16 + lw, csp[ct]);
        }
    }
}

// ---------------- K1 fallback (VALU, small ws) ----------------
__global__ __launch_bounds__(256) void k_assign_valu(
    const float* __restrict__ F, const float* __restrict__ W,
    const float* __restrict__ B, float* __restrict__ S, int N)
{
    __shared__ float Wl[DF * KC];
    for (int i = threadIdx.x; i < DF * KC; i += 256) Wl[i] = W[i];
    __syncthreads();
    const int lane = threadIdx.x & 63;
    const int wv = threadIdx.x >> 6;
    const float bv = B[lane];
    for (int row = blockIdx.x * 4 + wv; row < N; row += gridDim.x * 4) {
        const float* fp = F + (size_t)row * DF;
        float acc = bv;
        for (int d = 0; d < DF; ++d) acc = fmaf(fp[d], Wl[d * KC + lane], acc);
        float m = acc;
        #pragma unroll
        for (int off = 32; off; off >>= 1) m = fmaxf(m, __shfl_xor(m, off, 64));
        float e = expf(acc - m);
        float s = waveReduceSum(e);
        S[(size_t)row * KC + lane] = e / s;
    }
}

// ---------------- K2 (half-K pass): tr += sum_e v*<Sh_r,Sh_c>; SdH[k]; ne ----
// Sh: [N][32] bf16 (one K-half, 3.2 MB -> L2-resident).
// Lanes 0-31 process even edges (k=lane), lanes 32-63 odd edges (k=lane-32).
__global__ __launch_bounds__(256) void k_edgeH(
    const int* __restrict__ rF, const int* __restrict__ cF, const float* __restrict__ vF, int EF,
    const int* __restrict__ rR, const int* __restrict__ cR, const float* __restrict__ vR, int ER,
    const int* __restrict__ rB, const int* __restrict__ cB, const float* __restrict__ vB, int EB,
    const __hip_bfloat16* __restrict__ Sh,
    float* __restrict__ scal, float* __restrict__ SdH, int addNe)
{
    __shared__ float sdl[3][4][32];
    __shared__ float red[4][6];
    const int lane = threadIdx.x & 63;
    const int wv = threadIdx.x >> 6;
    const int lk = lane & 31;
    const int e2 = lane >> 5;
    const int wid = (blockIdx.x * blockDim.x + threadIdx.x) >> 6;
    const int nw = (gridDim.x * blockDim.x) >> 6;
    const int chF = (EF + 63) >> 6, chR = (ER + 63) >> 6, chB = (EB + 63) >> 6;
    const int tot = chF + chR + chB;
    float tr0 = 0.f, tr1 = 0.f, tr2 = 0.f;
    float sd0 = 0.f, sd1 = 0.f, sd2 = 0.f;
    float ne0 = 0.f, ne1 = 0.f, ne2 = 0.f;
    for (int ch = wid; ch < tot; ch += nw) {
        const int *rp, *cp; const float* vp; int base, len, seg;
        if (ch < chF)            { rp = rF; cp = cF; vp = vF; base = ch << 6;               len = EF; seg = 0; }
        else if (ch < chF + chR) { rp = rR; cp = cR; vp = vR; base = (ch - chF) << 6;       len = ER; seg = 1; }
        else                     { rp = rB; cp = cB; vp = vB; base = (ch - chF - chR) << 6; len = EB; seg = 2; }
        const int rem = len - base;   // >= 1
        float nev = 0.f;
        if (addNe) { int idx = base + lane; if (idx < len) nev = vp[idx]; }
        float t = 0.f, s = 0.f;
        #pragma unroll 8
        for (int j2 = 0; j2 < 32; ++j2) {
            int e = 2 * j2 + e2;
            bool ok = e < rem;
            int ee = ok ? e : 0;
            int rr = rp[base + ee];            // 2-valued per wave: L1-resident broadcast
            int cc = cp[base + ee];
            float vv = vp[base + ee];
            if (!ok) vv = 0.f;
            float sr = __bfloat162float(Sh[(size_t)rr * 32 + lk]);
            float sc = __bfloat162float(Sh[(size_t)cc * 32 + lk]);
            t = fmaf(vv * sr, sc, t);
            s = fmaf(vv, sc, s);
        }
        if (seg == 0)      { tr0 += t; sd0 += s; ne0 += nev; }
        else if (seg == 1) { tr1 += t; sd1 += s; ne1 += nev; }
        else               { tr2 += t; sd2 += s; ne2 += nev; }
    }
    // fold the two edge-halves of each lane-pair for Sd (same k in both halves)
    sd0 += __shfl_xor(sd0, 32, 64);
    sd1 += __shfl_xor(sd1, 32, 64);
    sd2 += __shfl_xor(sd2, 32, 64);
    if (lane < 32) {
        sdl[0][wv][lk] = sd0;
        sdl[1][wv][lk] = sd1;
        sdl[2][wv][lk] = sd2;
    }
    float t0 = waveReduceSum(tr0), t1 = waveReduceSum(tr1), t2 = waveReduceSum(tr2);
    float n0 = waveReduceSum(ne0), n1 = waveReduceSum(ne1), n2 = waveReduceSum(ne2);
    if (lane == 0) {
        red[wv][0] = t0; red[wv][1] = t1; red[wv][2] = t2;
        red[wv][3] = n0; red[wv][4] = n1; red[wv][5] = n2;
    }
    __syncthreads();
    const int tid = threadIdx.x;
    if (tid < 96) {
        int s2 = tid >> 5, k = tid & 31;
        float a = sdl[s2][0][k] + sdl[s2][1][k] + sdl[s2][2][k] + sdl[s2][3][k];
        atomicAdd(SdH + s2 * KC + k, a);
    } else if (tid < 96 + 6) {
        int q = tid - 96;   // 0..2 tr, 3..5 ne (ne only added when addNe pass)
        float a = red[0][q] + red[1][q] + red[2][q] + red[3][q];
        if (q < 3 || addNe) atomicAdd(scal + q, a);
    }
}

// ---------------- K2 fallback (f32 S, all 3 sets, shfl broadcast) ----------------
__global__ __launch_bounds__(256) void k_edge3(
    const int* __restrict__ rF, const int* __restrict__ cF, const float* __restrict__ vF, int EF,
    const int* __restrict__ rR, const int* __restrict__ cR, const float* __restrict__ vR, int ER,
    const int* __restrict__ rB, const int* __restrict__ cB, const float* __restrict__ vB, int EB,
    const float* __restrict__ S, float* __restrict__ scal, float* __restrict__ Sd)
{
    __shared__ float sdl[3][4][KC];
    __shared__ float red[4][6];
    const int lane = threadIdx.x & 63;
    const int wv = threadIdx.x >> 6;
    const int wid = (blockIdx.x * blockDim.x + threadIdx.x) >> 6;
    const int nw = (gridDim.x * blockDim.x) >> 6;
    const int chF = (EF + 63) >> 6, chR = (ER + 63) >> 6, chB = (EB + 63) >> 6;
    const int tot = chF + chR + chB;
    float tr0 = 0.f, tr1 = 0.f, tr2 = 0.f;
    float sd0 = 0.f, sd1 = 0.f, sd2 = 0.f;
    float ne0 = 0.f, ne1 = 0.f, ne2 = 0.f;
    for (int ch = wid; ch < tot; ch += nw) {
        const int *rp, *cp; const float* vp; int base, len, seg;
        if (ch < chF)            { rp = rF; cp = cF; vp = vF; base = ch << 6;               len = EF; seg = 0; }
        else if (ch < chF + chR) { rp = rR; cp = cR; vp = vR; base = (ch - chF) << 6;       len = ER; seg = 1; }
        else                     { rp = rB; cp = cB; vp = vB; base = (ch - chF - chR) << 6; len = EB; seg = 2; }
        int idx = base + lane;
        bool ok = idx < len;
        int r0 = ok ? rp[idx] : 0;
        int c0 = ok ? cp[idx] : 0;
        float v0 = ok ? vp[idx] : 0.f;
        float t = 0.f, s = 0.f;
        #pragma unroll 8
        for (int j = 0; j < 64; ++j) {
            int rr = __shfl(r0, j, 64);
            int cc = __shfl(c0, j, 64);
            float vv = __shfl(v0, j, 64);
            float sr = ldS(S + (size_t)rr * KC + lane);
            float sc = ldS(S + (size_t)cc * KC + lane);
            t = fmaf(vv * sr, sc, t);
            s = fmaf(vv, sc, s);
        }
        if (seg == 0)      { tr0 += t; sd0 += s; ne0 += v0; }
        else if (seg == 1) { tr1 += t; sd1 += s; ne1 += v0; }
        else               { tr2 += t; sd2 += s; ne2 += v0; }
    }
    sdl[0][wv][lane] = sd0;
    sdl[1][wv][lane] = sd1;
    sdl[2][wv][lane] = sd2;
    float t0 = waveReduceSum(tr0), t1 = waveReduceSum(tr1), t2 = waveReduceSum(tr2);
    float n0 = waveReduceSum(ne0), n1 = waveReduceSum(ne1), n2 = waveReduceSum(ne2);
    if (lane == 0) {
        red[wv][0] = t0; red[wv][1] = t1; red[wv][2] = t2;
        red[wv][3] = n0; red[wv][4] = n1; red[wv][5] = n2;
    }
    __syncthreads();
    if (threadIdx.x < KC) {
        #pragma unroll
        for (int s2 = 0; s2 < 3; ++s2) {
            float a = sdl[s2][0][threadIdx.x] + sdl[s2][1][threadIdx.x]
                    + sdl[s2][2][threadIdx.x] + sdl[s2][3][threadIdx.x];
            atomicAdd(Sd + s2 * KC + threadIdx.x, a);
        }
    } else if (threadIdx.x < KC + 6) {
        int q = threadIdx.x - KC;
        float a = red[0][q] + red[1][q] + red[2][q] + red[3][q];
        atomicAdd(scal + q, a);
    }
}

// ---------------- K3 (fallback only): cs[k] = sum_n S[n,k] ----------------
__global__ __launch_bounds__(256) void k_cs(
    const float* __restrict__ S, float* __restrict__ cs, int N)
{
    const int lane = threadIdx.x & 63;
    const int wid = (blockIdx.x * blockDim.x + threadIdx.x) >> 6;
    const int nw = (gridDim.x * blockDim.x) >> 6;
    float a = 0.f;
    for (int row = wid; row < N; row += nw)
        a += S[(size_t)row * KC + lane];
    atomicAdd(cs + lane, a);
}

// ---------------- K4: P[k,d] = sum_n S[n,k] * F[n,d] ----------------
__global__ __launch_bounds__(256) void k_pool(
    const float* __restrict__ S, const float* __restrict__ F,
    float* __restrict__ P, int N)
{
    const int d = threadIdx.x;
    float acc[KC];
    #pragma unroll
    for (int k = 0; k < KC; ++k) acc[k] = 0.f;
    int rowsPer = (N + gridDim.x - 1) / gridDim.x;
    int n0 = blockIdx.x * rowsPer;
    int n1 = min(N, n0 + rowsPer);
    #pragma unroll 2
    for (int n = n0; n < n1; ++n) {
        float fv = F[(size_t)n * DF + d];
        const float* sp = S + (size_t)n * KC;
        #pragma unroll
        for (int k = 0; k < KC; ++k)
            acc[k] = fmaf(sp[k], fv, acc[k]);
    }
    #pragma unroll
    for (int k = 0; k < KC; ++k) atomicAdd(P + k * DF + d, acc[k]);
}

// ---------------- K5: epilogue ----------------
__global__ __launch_bounds__(256) void k_final(
    const float* __restrict__ P, const float* __restrict__ cs,
    const float* __restrict__ scal,
    const float* __restrict__ Sd,
    const float* __restrict__ lamdaPtr,
    float* __restrict__ out, int N, int lossIdx)
{
    const float SC = 1.0507009873554805f, AL = 1.6732632423543772f;
    for (int i = threadIdx.x + blockIdx.x * blockDim.x; i < KC * DF; i += gridDim.x * blockDim.x) {
        int k = i / DF;
        float x = P[i] / cs[k];
        float y = x > 0.f ? SC * x : SC * AL * (expf(x) - 1.f);
        out[i] = y;
    }
    if (blockIdx.x == 0 && threadIdx.x == 0) {
        float trF = scal[0], trR = scal[1], trB = scal[2];
        float neF = scal[3], neR = scal[4], neB = scal[5];
        float two_m = neF;
        float sdf = 0.f, sdr = 0.f, sdb = 0.f, csn = 0.f;
        for (int k = 0; k < KC; ++k) {
            sdf += Sd[0 * KC + k] * Sd[0 * KC + k];
            sdr += Sd[1 * KC + k] * Sd[1 * KC + k];
            sdb += Sd[2 * KC + k] * Sd[2 * KC + k];
            csn += cs[k] * cs[k];
        }
        float lossF = -(trF - sdf / 2.f / neF) / 2.f / two_m;
        float lossR = -(trR - sdr / 2.f / neR) / 2.f / two_m;
        float lossB = -(trB - sdb / 2.f / neB) / 2.f / two_m;
        float fairness = fabsf(lamdaPtr[0] * (lossR - lossB));
        float collapse = sqrtf(csn) / (float)N * sqrtf((float)KC) - 1.f;
        out[lossIdx] = fairness + lossF + 0.1f * collapse;
    }
}

extern "C" void kernel_launch(void* const* d_in, const int* in_sizes, int n_in,
                              void* d_out, int out_size, void* d_ws, size_t ws_size,
                              hipStream_t stream) {
    float* out = (float*)d_out;

    const int expected_sizes[13] = {12800000, 1600000, 1600000, 1600000,
                                    800000, 800000, 800000, 800000, 800000, 800000,
                                    16384, 64, 1};
    bool sizes_ok = (n_in == 13) && (out_size == 16384 + 12800000 / DF * KC + 1);
    if (sizes_ok) for (int i = 0; i < 13; ++i) if (in_sizes[i] != expected_sizes[i]) sizes_ok = false;
    if (!sizes_ok) {
        k_sentinel<<<64, 256, 0, stream>>>(out, 22222.0f, KC * DF);
        return;
    }

    const float* F  = (const float*)d_in[0];
    const int*   rF = (const int*)  d_in[1];
    const int*   cF = (const int*)  d_in[2];
    const float* vF = (const float*)d_in[3];
    const int*   rR = (const int*)  d_in[4];
    const int*   cR = (const int*)  d_in[5];
    const float* vR = (const float*)d_in[6];
    const int*   rB = (const int*)  d_in[7];
    const int*   cB = (const int*)  d_in[8];
    const float* vB = (const float*)d_in[9];
    const float* W  = (const float*)d_in[10];
    const float* B  = (const float*)d_in[11];
    const float* lam= (const float*)d_in[12];

    const int E   = in_sizes[1];
    const int E2r = in_sizes[4];
    const int E2b = in_sizes[7];
    const int N   = in_sizes[0] / DF;

    float* S = out + KC * DF;   // S [N,K] f32 in the output buffer

    // ws: [f32: scal 16 | cs 64 | Sd 192 | P 16384] [W2 hi/lo 65536 B] [S16 k-split N*K*2 B]
    const size_t f32Bytes = (size_t)(16 + KC + 3 * KC + KC * DF) * sizeof(float);
    const size_t w2Bytes  = (size_t)2 * DF * KC * sizeof(ushort);
    const size_t s16Bytes = (size_t)N * KC * sizeof(__hip_bfloat16);
    const bool useMfma = ws_size >= f32Bytes + w2Bytes;
    const bool useBf16 = ws_size >= f32Bytes + w2Bytes + s16Bytes;
    if (ws_size < f32Bytes) {
        k_sentinel<<<64, 256, 0, stream>>>(out, 11111.0f, KC * DF);
        return;
    }
    float* scal = (float*)d_ws;
    float* cs   = scal + 16;
    float* Sd   = cs + KC;
    float* P    = Sd + 3 * KC;
    ushort* W2  = (ushort*)((char*)d_ws + f32Bytes);
    __hip_bfloat16* S16 = (__hip_bfloat16*)((char*)d_ws + f32Bytes + w2Bytes);
    const size_t halfStride = (size_t)N * 32;
    const int zeroCount = 16 + KC + 3 * KC + KC * DF;

    k_zero<<<64, 256, 0, stream>>>(scal, zeroCount);
    if (useMfma) {
        const int NT = (N + 15) >> 4;
        k_prepW<<<64, 256, 0, stream>>>(W, W2);
        k_assign_mfma<<<(NT + 3) / 4, 256, 0, stream>>>(F, W2, B, S, S16, cs, N, useBf16 ? 1 : 0);
    } else {
        k_assign_valu<<<2048, 256, 0, stream>>>(F, W, B, S, N);
        k_cs<<<1024, 256, 0, stream>>>(S, cs, N);
    }
    if (useBf16) {
        k_edgeH<<<2048, 256, 0, stream>>>(
            rF, cF, vF, E, rR, cR, vR, E2r, rB, cB, vB, E2b,
            S16, scal, Sd, 1);
        k_edgeH<<<2048, 256, 0, stream>>>(
            rF, cF, vF, E, rR, cR, vR, E2r, rB, cB, vB, E2b,
            S16 + halfStride, scal, Sd + 32, 0);
    } else {
        k_edge3<<<2048, 256, 0, stream>>>(
            rF, cF, vF, E, rR, cR, vR, E2r, rB, cB, vB, E2b, S, scal, Sd);
    }
    k_pool<<<256, 256, 0, stream>>>(S, F, P, N);
    k_final<<<64, 256, 0, stream>>>(P, cs, scal, Sd, lam, out, N, out_size - 1);
}